// Round 5
// baseline (153.590 us; speedup 1.0000x reference)
//
#include <hip/hip_runtime.h>
#include <math.h>

#define BATCH     262144
#define NASSETS   128
#define TILE_ROWS 128                    // rows per K1 block
#define NBLK      (BATCH / TILE_ROWS)    // 2048
#define SCHUNK    32                     // scan / replay chunk
#define NSC       (BATCH / SCHUNK)       // 8192
#define ETA       0.01
#define CDECAY    0.99
#define EPS       1e-8
#define LPAD      33

// Transposed carry layout: chunk c stored at (c&31)*256 + (c>>5) so the
// 256-thread scan reads/writes coalesced (lane l owns chunks [32l,32l+32)).
__device__ __forceinline__ int tpos(int c) { return (c & 31) * 256 + (c >> 5); }

__device__ __forceinline__ float dot4(float4 a, float4 b) {
  return a.x * b.x + a.y * b.y + a.z * b.z + a.w * b.w;
}

// K1: streaming dots + per-32-row carries; the LAST block to finish also
// runs the global carry scan (deadlock-free: no dispatch-order assumption).
__global__ __launch_bounds__(256, 8) void k_rows(
    const float* __restrict__ W, const float* __restrict__ X,
    float* __restrict__ R, double* __restrict__ SAt, double* __restrict__ SBt,
    const float* __restrict__ A0p, const float* __restrict__ B0p,
    double* __restrict__ CAt, double* __restrict__ CBt,
    unsigned* __restrict__ cnt2) {
  __shared__ float part[TILE_ROWS * LPAD];
  const int t   = threadIdx.x;
  const int blk = blockIdx.x;
  const float4* W4 = reinterpret_cast<const float4*>(W) + (size_t)blk * 4096;
  const float4* X4 = reinterpret_cast<const float4*>(X) + (size_t)blk * 4096;

  // Phase 1: 16 independent float4-pair loads -> padded LDS (conflict-free).
  #pragma unroll
  for (int p = 0; p < 16; ++p) {
    const int idx = p * 256 + t;
    part[(idx >> 5) * LPAD + (idx & 31)] = dot4(W4[idx], X4[idx]);
  }
  __syncthreads();

  // Phase 2: 128 threads finish rows + 32-row group carries via shfl.
  if (t < TILE_ROWS) {
    float sum = 0.f;
    #pragma unroll
    for (int j = 0; j < 32; ++j) sum += part[t * LPAD + j];
    R[(size_t)blk * TILE_ROWS + t] = sum;

    const int e = 31 - (t & 31);            // wgt = ETA * c^e via square-select
    const double c1 = CDECAY, c2 = c1*c1, c4 = c2*c2, c8 = c4*c4, c16 = c8*c8;
    double wgt = ETA;
    if (e & 1)  wgt *= c1;
    if (e & 2)  wgt *= c2;
    if (e & 4)  wgt *= c4;
    if (e & 8)  wgt *= c8;
    if (e & 16) wgt *= c16;
    const double r = (double)sum;
    double sA = wgt * r, sB = wgt * r * r;
    sA += __shfl_xor(sA, 16, 64); sB += __shfl_xor(sB, 16, 64);
    sA += __shfl_xor(sA,  8, 64); sB += __shfl_xor(sB,  8, 64);
    sA += __shfl_xor(sA,  4, 64); sB += __shfl_xor(sB,  4, 64);
    sA += __shfl_xor(sA,  2, 64); sB += __shfl_xor(sB,  2, 64);
    sA += __shfl_xor(sA,  1, 64); sB += __shfl_xor(sB,  1, 64);
    if ((t & 31) == 0) {
      const int c = blk * 4 + (t >> 5);
      SAt[tpos(c)] = sA;
      SBt[tpos(c)] = sB;
    }
  }
  __syncthreads();

  // Last-finisher election (device-scope; cnt2 zeroed by host-side memset).
  __shared__ unsigned lastf;
  if (t == 0) {
    __threadfence();                        // publish SAt/SBt
    lastf = atomicAdd(cnt2, 1u);
  }
  __syncthreads();
  if (lastf != NBLK - 1) return;
  if (t == 0) __threadfence();              // acquire all blocks' SAt/SBt
  __syncthreads();

  // ---- Global scan of the 8192 chunk carries (256 threads, both arrays) ----
  const int l = t, lw = t & 63, w = t >> 6;
  __shared__ double wtot[4], wcar[4];

  double m = CDECAY;                    // -> c^32 (per-chunk factor)
  #pragma unroll
  for (int q = 0; q < 5; ++q) m = m * m;
  double g = m;                         // -> c^1024 (per-lane factor)
  #pragma unroll
  for (int q = 0; q < 5; ++q) g = g * g;
  double F = g;                         // -> g^64 (per-wave factor)
  #pragma unroll
  for (int q = 0; q < 6; ++q) F = F * F;
  double glw = 1.0, gl = 1.0, p2 = g;   // g^lw and g^l via bit-select
  #pragma unroll
  for (int b = 0; b < 8; ++b) {
    if (lw & (1 << b)) glw *= p2;
    if (l  & (1 << b)) gl  *= p2;
    p2 = p2 * p2;
  }

  #pragma unroll 1
  for (int arr = 0; arr < 2; ++arr) {
    const double* St = arr ? SBt : SAt;
    double*       Ct = arr ? CBt : CAt;
    const double init0 = arr ? (double)B0p[0] : (double)A0p[0];

    double y = 0.0;                     // compose this lane's 32 chunks
    for (int i = 0; i < 32; ++i) y = m * y + St[i * 256 + l];

    double s = y, f = g;                // wave-level scan (factor g, squares)
    #pragma unroll
    for (int d = 1; d < 64; d <<= 1) {
      double u = __shfl_up(s, d, 64);
      if (lw >= d) s += f * u;
      f *= f;
    }
    if (lw == 63) wtot[w] = s;
    __syncthreads();
    if (l == 0) {
      double Wc = 0.0;
      for (int ww = 0; ww < 4; ++ww) { wcar[ww] = Wc; Wc = wtot[ww] + F * Wc; }
    }
    __syncthreads();
    double aIn = __shfl_up(s, 1, 64);
    if (lw == 0) aIn = 0.0;
    double A = aIn + wcar[w] * glw;     // state entering chunk 32l
    double h = init0 * gl;              // homogeneous A0/B0 term at chunk 32l
    for (int i = 0; i < 32; ++i) {
      Ct[i * 256 + l] = A + h;
      A = m * A + St[i * 256 + l];
      h *= m;
    }
    __syncthreads();
  }
}

// K2: 32 blocks x 256 threads, all active; block b replays chunks
// [256b, 256b+256). R staged via padded LDS. f64 recurrence + numerator,
// f32 rsqrt for var^-1.5 (per-term abs err <=5e-4, /262144 on the mean ->
// far below the 4e-5 threshold). Last block finalizes output.
__global__ __launch_bounds__(256) void k_dsr(
    const float* __restrict__ R, const double* __restrict__ CAt,
    const double* __restrict__ CBt, double* __restrict__ acc,
    unsigned* __restrict__ cnt, float* __restrict__ out) {
  __shared__ float lr[256 * LPAD];      // 33.8 KB
  const int t  = threadIdx.x;
  const int j0 = blockIdx.x * 256;
  const float* Rb = R + (size_t)j0 * SCHUNK;
  #pragma unroll
  for (int q = 0; q < 32; ++q) {        // coalesced global -> padded LDS
    const int fi = q * 256 + t;
    lr[((q * 8) + (t >> 5)) * LPAD + (t & 31)] = Rb[fi];
  }
  __syncthreads();

  const int c = j0 + t;
  double A = CAt[tpos(c)], B = CBt[tpos(c)];
  double sum = 0.0;
  #pragma unroll
  for (int k = 0; k < SCHUNK; ++k) {
    const double rv = (double)lr[t * LPAD + k];
    const double dA = ETA * (rv - A);
    const double dB = ETA * (rv * rv - B);
    double var = B - A * A;
    var = var > EPS ? var : EPS;
    const double num = B * dA - 0.5 * A * dB;
    const float inv = rsqrtf((float)var);      // var^-0.5 (f32)
    sum += num * (double)(inv * inv * inv);    // num * var^-1.5
    A += dA;
    B += dB;
  }
  sum += __shfl_xor(sum, 32, 64);
  sum += __shfl_xor(sum, 16, 64);
  sum += __shfl_xor(sum,  8, 64);
  sum += __shfl_xor(sum,  4, 64);
  sum += __shfl_xor(sum,  2, 64);
  sum += __shfl_xor(sum,  1, 64);
  __shared__ double red[4];
  const int wave = t >> 6, lane = t & 63;
  if (lane == 0) red[wave] = sum;
  __syncthreads();
  if (t == 0) {
    atomicAdd(acc, red[0] + red[1] + red[2] + red[3]);
    __threadfence();
    const unsigned old = atomicAdd(cnt, 1u);
    if (old == gridDim.x - 1) {
      const double v = atomicAdd(acc, 0.0);   // atomic read: all adds visible
      out[0] = (float)(-v / (double)BATCH);
    }
  }
}

extern "C" void kernel_launch(void* const* d_in, const int* in_sizes, int n_in,
                              void* d_out, int out_size, void* d_ws, size_t ws_size,
                              hipStream_t stream) {
  const float* W  = (const float*)d_in[0];
  const float* X  = (const float*)d_in[1];
  const float* A0 = (const float*)d_in[2];
  const float* B0 = (const float*)d_in[3];

  char* ws = (char*)d_ws;
  float*  R   = (float*)ws;                                // 1 MB
  double* SAt = (double*)(ws + (size_t)BATCH * 4);         // 64 KB each
  double* SBt = SAt + NSC;
  double* CAt = SBt + NSC;
  double* CBt = CAt + NSC;
  double* acc = CBt + NSC;                                 // 8 B
  unsigned* cnt  = (unsigned*)(acc + 1);                   // k_dsr counter
  unsigned* cnt2 = cnt + 1;                                // k_rows counter

  hipMemsetAsync(acc, 0, 16, stream);   // acc, cnt, cnt2
  k_rows<<<NBLK, 256, 0, stream>>>(W, X, R, SAt, SBt, A0, B0, CAt, CBt, cnt2);
  k_dsr<<<NSC / 256, 256, 0, stream>>>(R, CAt, CBt, acc, cnt, (float*)d_out);
}

// Round 6
// 56.632 us; speedup vs baseline: 2.7121x; 2.7121x over previous
//
#include <hip/hip_runtime.h>
#include <math.h>

#define BATCH     262144
#define NASSETS   128
#define TILE_ROWS 128                    // rows per K1 block
#define NBLK      (BATCH / TILE_ROWS)    // 2048
#define SCHUNK    32                     // scan / replay chunk (rows)
#define NSC       (BATCH / SCHUNK)       // 8192 chunks
#define TBLK      64                     // k_tail blocks
#define TCH       (NSC / TBLK)           // 128 chunks per tail block
#define ETA       0.01
#define CDECAY    0.99
#define EPS       1e-8
#define LPAD      33

__device__ __forceinline__ float dot4(float4 a, float4 b) {
  return a.x * b.x + a.y * b.y + a.z * b.z + a.w * b.w;
}

// base^e by square-multiply, e < 8192 (13 bits). Underflow to 0 is exact-enough decay.
__device__ __forceinline__ double mpow(double base, int e) {
  double r = 1.0, p = base;
  #pragma unroll
  for (int b = 0; b < 13; ++b) { if (e & (1 << b)) r *= p; p *= p; }
  return r;
}

// K1: streaming dot products (proven structure; no atomics, no fences).
// Writes R and per-32-row carries SA/SB LINEARLY (chunk c = blk*4+g).
__global__ __launch_bounds__(256) void k_rows(
    const float* __restrict__ W, const float* __restrict__ X,
    float* __restrict__ R, double* __restrict__ SA, double* __restrict__ SB) {
  __shared__ float part[TILE_ROWS * LPAD];
  const int t   = threadIdx.x;
  const int blk = blockIdx.x;
  const float4* W4 = reinterpret_cast<const float4*>(W) + (size_t)blk * 4096;
  const float4* X4 = reinterpret_cast<const float4*>(X) + (size_t)blk * 4096;

  #pragma unroll
  for (int p = 0; p < 16; ++p) {
    const int idx = p * 256 + t;
    part[(idx >> 5) * LPAD + (idx & 31)] = dot4(W4[idx], X4[idx]);
  }
  __syncthreads();

  if (t < TILE_ROWS) {
    float sum = 0.f;
    #pragma unroll
    for (int j = 0; j < 32; ++j) sum += part[t * LPAD + j];
    R[(size_t)blk * TILE_ROWS + t] = sum;

    const int e = 31 - (t & 31);            // wgt = ETA * c^e via square-select
    const double c1 = CDECAY, c2 = c1*c1, c4 = c2*c2, c8 = c4*c4, c16 = c8*c8;
    double wgt = ETA;
    if (e & 1)  wgt *= c1;
    if (e & 2)  wgt *= c2;
    if (e & 4)  wgt *= c4;
    if (e & 8)  wgt *= c8;
    if (e & 16) wgt *= c16;
    const double r = (double)sum;
    double sA = wgt * r, sB = wgt * r * r;
    sA += __shfl_xor(sA, 16, 64); sB += __shfl_xor(sB, 16, 64);
    sA += __shfl_xor(sA,  8, 64); sB += __shfl_xor(sB,  8, 64);
    sA += __shfl_xor(sA,  4, 64); sB += __shfl_xor(sB,  4, 64);
    sA += __shfl_xor(sA,  2, 64); sB += __shfl_xor(sB,  2, 64);
    sA += __shfl_xor(sA,  1, 64); sB += __shfl_xor(sB,  1, 64);
    if ((t & 31) == 0) SA[blk * 4 + (t >> 5)] = sA;
    if ((t & 31) == 0) SB[blk * 4 + (t >> 5)] = sB;
  }
}

// K2 (k_tail): 64 INDEPENDENT blocks x 128 threads. Block b owns chunks
// [128b, 128b+128). Incoming carry is recomputed redundantly from the 256
// chunk-carries preceding the block (weights m^(255-j)); older terms carry
// factor c^8192 ~ 1.6e-36 -> dropped (<< f64 ulp, << 4e-5 threshold).
// Then: local shfl scan, f64 replay with f32 rsqrt, atomic finalize.
__global__ __launch_bounds__(128) void k_tail(
    const float* __restrict__ R, const double* __restrict__ SA,
    const double* __restrict__ SB, const float* __restrict__ A0p,
    const float* __restrict__ B0p, double* __restrict__ acc,
    unsigned* __restrict__ cnt, float* __restrict__ out) {
  __shared__ float  lr[TCH * LPAD];     // 16.9 KB
  __shared__ double wred[4];
  const int t = threadIdx.x;            // 0..127
  const int b = blockIdx.x;             // 0..63
  const int lane = t & 63, w = t >> 6;

  // Stage this block's 4096 R values -> padded LDS (coalesced, conflict-free).
  const float* Rb = R + (size_t)b * (TCH * SCHUNK);
  #pragma unroll
  for (int q = 0; q < 32; ++q) {
    const int fi = q * 128 + t;
    lr[(fi >> 5) * LPAD + (fi & 31)] = Rb[fi];
  }

  double m = CDECAY;                    // -> c^32 (per-chunk factor)
  #pragma unroll
  for (int q = 0; q < 5; ++q) m = m * m;

  // Incoming carry from the 256-chunk predecessor window.
  const int wbase = b * TCH - 256;      // global chunk index of window j=0
  double xA = 0.0, xB = 0.0;
  #pragma unroll
  for (int s = 0; s < 2; ++s) {
    const int j = t + s * 128;
    const int g = wbase + j;
    if (g >= 0) {
      const double wgt = mpow(m, 255 - j);
      xA += wgt * SA[g];
      xB += wgt * SB[g];
    }
  }
  #pragma unroll
  for (int d = 32; d >= 1; d >>= 1) {
    xA += __shfl_xor(xA, d, 64);
    xB += __shfl_xor(xB, d, 64);
  }
  if (lane == 0) { wred[w * 2] = xA; wred[w * 2 + 1] = xB; }
  __syncthreads();
  xA = wred[0] + wred[2];
  xB = wred[1] + wred[3];
  __syncthreads();

  // Own chunk values + exclusive scan (factor m) across the 128 chunks.
  const int c = b * TCH + t;
  double iA = SA[c], iB = SB[c], f = m;
  #pragma unroll
  for (int d = 1; d < 64; d <<= 1) {
    const double uA = __shfl_up(iA, d, 64);
    const double uB = __shfl_up(iB, d, 64);
    if (lane >= d) { iA += f * uA; iB += f * uB; }
    f *= f;
  }
  double eA = __shfl_up(iA, 1, 64);
  double eB = __shfl_up(iB, 1, 64);
  if (lane == 0) { eA = 0.0; eB = 0.0; }
  if (lane == 63) { wred[w * 2] = iA; wred[w * 2 + 1] = iB; }
  __syncthreads();
  const double mlane = mpow(m, lane);
  if (w == 1) { eA += wred[0] * mlane; eB += wred[1] * mlane; }

  // State entering chunk c (incoming carry decayed to local t + homog. term).
  const double mt  = mpow(m, t);
  const double hmg = mpow(m, b * TCH + t);
  double A = eA + xA * mt + (double)A0p[0] * hmg;
  double B = eB + xB * mt + (double)B0p[0] * hmg;

  // Replay 32 rows: f64 recurrence + numerator, f32 rsqrt for var^-1.5.
  double sum = 0.0;
  #pragma unroll
  for (int k = 0; k < SCHUNK; ++k) {
    const double rv = (double)lr[t * LPAD + k];
    const double dA = ETA * (rv - A);
    const double dB = ETA * (rv * rv - B);
    double var = B - A * A;
    var = var > EPS ? var : EPS;
    const double num = B * dA - 0.5 * A * dB;
    const float inv = rsqrtf((float)var);
    sum += num * (double)(inv * inv * inv);
    A += dA;
    B += dB;
  }
  #pragma unroll
  for (int d = 32; d >= 1; d >>= 1) sum += __shfl_xor(sum, d, 64);
  __syncthreads();
  if (lane == 0) wred[w] = sum;
  __syncthreads();
  if (t == 0) {
    atomicAdd(acc, wred[0] + wred[1]);
    __threadfence();
    const unsigned old = atomicAdd(cnt, 1u);
    if (old == TBLK - 1) {
      const double v = atomicAdd(acc, 0.0);   // atomic read: all adds visible
      out[0] = (float)(-v / (double)BATCH);
    }
  }
}

extern "C" void kernel_launch(void* const* d_in, const int* in_sizes, int n_in,
                              void* d_out, int out_size, void* d_ws, size_t ws_size,
                              hipStream_t stream) {
  const float* W  = (const float*)d_in[0];
  const float* X  = (const float*)d_in[1];
  const float* A0 = (const float*)d_in[2];
  const float* B0 = (const float*)d_in[3];

  char* ws = (char*)d_ws;
  float*  R  = (float*)ws;                                 // 1 MB
  double* SA = (double*)(ws + (size_t)BATCH * 4);          // 64 KB
  double* SB = SA + NSC;                                   // 64 KB
  double* acc = SB + NSC;                                  // 8 B
  unsigned* cnt = (unsigned*)(acc + 1);                    // 4 B

  hipMemsetAsync(acc, 0, 16, stream);   // acc + cnt
  k_rows<<<NBLK, 256, 0, stream>>>(W, X, R, SA, SB);
  k_tail<<<TBLK, 128, 0, stream>>>(R, SA, SB, A0, B0, acc, cnt, (float*)d_out);
}

// Round 7
// 54.775 us; speedup vs baseline: 2.8040x; 1.0339x over previous
//
#include <hip/hip_runtime.h>
#include <math.h>

#define BATCH     262144
#define NASSETS   128
#define TILE_ROWS 64                     // rows per K1 block
#define NBLK      (BATCH / TILE_ROWS)    // 4096
#define SCHUNK    32                     // scan / replay chunk (rows)
#define NSC       (BATCH / SCHUNK)       // 8192 chunks
#define TBLK      64                     // k_tail blocks
#define TCH       (NSC / TBLK)           // 128 chunks per tail block
#define ETA       0.01
#define CDECAY    0.99
#define EPS       1e-8
#define LPAD      33

__device__ __forceinline__ float dot4(float4 a, float4 b) {
  return a.x * b.x + a.y * b.y + a.z * b.z + a.w * b.w;
}

// base^e by square-multiply, e < 8192 (13 bits).
__device__ __forceinline__ double mpow(double base, int e) {
  double r = 1.0, p = base;
  #pragma unroll
  for (int b = 0; b < 13; ++b) { if (e & (1 << b)) r *= p; p *= p; }
  return r;
}

// K1: global_load_lds staging (no VGPR round-trip; DMA queue provides the
// MLP the compiler refused to give reg-staged loads — VGPR pinned at 32-36
// across R2-R4). 64-row tiles: W 32KB + X 32KB direct to LDS, barrier,
// dot + padded-LDS reduce. 75KB LDS -> 2 blocks/CU alternating DMA/compute.
__global__ __launch_bounds__(256) void k_rows(
    const float* __restrict__ W, const float* __restrict__ X,
    float* __restrict__ R, double* __restrict__ SA, double* __restrict__ SB) {
  __shared__ float wbuf[TILE_ROWS * NASSETS];   // 32 KB
  __shared__ float xbuf[TILE_ROWS * NASSETS];   // 32 KB
  __shared__ float part[TILE_ROWS * LPAD];      // 8.4 KB
  __shared__ float hs[256];                     // 1 KB
  const int t   = threadIdx.x;
  const int blk = blockIdx.x;
  const int w   = t >> 6, l = t & 63;
  const float4* W4 = reinterpret_cast<const float4*>(W) + (size_t)blk * 1024;
  const float4* X4 = reinterpret_cast<const float4*>(X) + (size_t)blk * 1024;

  // Stage: 64 x 1KB DMA instrs (16B/lane, linear LDS dest = base + lane*16).
  #pragma unroll
  for (int j = 0; j < 8; ++j) {
    const int seg = w * 8 + j;                  // 0..31 (256-float segment)
    const float4* gw = W4 + seg * 64 + l;
    const float4* gx = X4 + seg * 64 + l;
    __builtin_amdgcn_global_load_lds(
        (const __attribute__((address_space(1))) void*)gw,
        (__attribute__((address_space(3))) void*)&wbuf[seg * 256], 16, 0, 0);
    __builtin_amdgcn_global_load_lds(
        (const __attribute__((address_space(1))) void*)gx,
        (__attribute__((address_space(3))) void*)&xbuf[seg * 256], 16, 0, 0);
  }
  __syncthreads();                              // drains vmcnt (DMA complete)

  // Partial dots: contiguous ds_read_b128 (conflict-free), padded writes.
  #pragma unroll
  for (int p = 0; p < 8; ++p) {
    const int idx = p * 256 + t;
    const float4 a = reinterpret_cast<const float4*>(wbuf)[idx];
    const float4 b = reinterpret_cast<const float4*>(xbuf)[idx];
    part[(idx >> 5) * LPAD + (idx & 31)] = dot4(a, b);
  }
  __syncthreads();

  // Quarter-row sums (all 256 threads), then 64 threads finish + carries.
  {
    const int row = t & 63, q = t >> 6;
    float s = 0.f;
    #pragma unroll
    for (int j = 0; j < 8; ++j) s += part[row * LPAD + q * 8 + j];
    hs[t] = s;
  }
  __syncthreads();
  if (t < TILE_ROWS) {
    const float sum = hs[t] + hs[t + 64] + hs[t + 128] + hs[t + 192];
    R[(size_t)blk * TILE_ROWS + t] = sum;

    const int e = 31 - (t & 31);            // wgt = ETA * c^e via square-select
    const double c1 = CDECAY, c2 = c1*c1, c4 = c2*c2, c8 = c4*c4, c16 = c8*c8;
    double wgt = ETA;
    if (e & 1)  wgt *= c1;
    if (e & 2)  wgt *= c2;
    if (e & 4)  wgt *= c4;
    if (e & 8)  wgt *= c8;
    if (e & 16) wgt *= c16;
    const double r = (double)sum;
    double sA = wgt * r, sB = wgt * r * r;
    sA += __shfl_xor(sA, 16, 64); sB += __shfl_xor(sB, 16, 64);
    sA += __shfl_xor(sA,  8, 64); sB += __shfl_xor(sB,  8, 64);
    sA += __shfl_xor(sA,  4, 64); sB += __shfl_xor(sB,  4, 64);
    sA += __shfl_xor(sA,  2, 64); sB += __shfl_xor(sB,  2, 64);
    sA += __shfl_xor(sA,  1, 64); sB += __shfl_xor(sB,  1, 64);
    if ((t & 31) == 0) {
      SA[blk * 2 + (t >> 5)] = sA;
      SB[blk * 2 + (t >> 5)] = sB;
    }
  }
}

// K2 (k_tail): 64 INDEPENDENT blocks x 128 threads (unchanged from R5).
// Incoming carry recomputed redundantly from the 256-chunk predecessor
// window (older terms carry c^8192 ~ 1.6e-36 -> dropped).
__global__ __launch_bounds__(128) void k_tail(
    const float* __restrict__ R, const double* __restrict__ SA,
    const double* __restrict__ SB, const float* __restrict__ A0p,
    const float* __restrict__ B0p, double* __restrict__ acc,
    unsigned* __restrict__ cnt, float* __restrict__ out) {
  __shared__ float  lr[TCH * LPAD];     // 16.9 KB
  __shared__ double wred[4];
  const int t = threadIdx.x;            // 0..127
  const int b = blockIdx.x;             // 0..63
  const int lane = t & 63, w = t >> 6;

  const float* Rb = R + (size_t)b * (TCH * SCHUNK);
  #pragma unroll
  for (int q = 0; q < 32; ++q) {
    const int fi = q * 128 + t;
    lr[(fi >> 5) * LPAD + (fi & 31)] = Rb[fi];
  }

  double m = CDECAY;                    // -> c^32 (per-chunk factor)
  #pragma unroll
  for (int q = 0; q < 5; ++q) m = m * m;

  // Incoming carry from the 256-chunk predecessor window.
  const int wbase = b * TCH - 256;
  double xA = 0.0, xB = 0.0;
  #pragma unroll
  for (int s = 0; s < 2; ++s) {
    const int j = t + s * 128;
    const int g = wbase + j;
    if (g >= 0) {
      const double wgt = mpow(m, 255 - j);
      xA += wgt * SA[g];
      xB += wgt * SB[g];
    }
  }
  #pragma unroll
  for (int d = 32; d >= 1; d >>= 1) {
    xA += __shfl_xor(xA, d, 64);
    xB += __shfl_xor(xB, d, 64);
  }
  if (lane == 0) { wred[w * 2] = xA; wred[w * 2 + 1] = xB; }
  __syncthreads();
  xA = wred[0] + wred[2];
  xB = wred[1] + wred[3];
  __syncthreads();

  // Own chunk values + exclusive scan (factor m) across the 128 chunks.
  const int c = b * TCH + t;
  double iA = SA[c], iB = SB[c], f = m;
  #pragma unroll
  for (int d = 1; d < 64; d <<= 1) {
    const double uA = __shfl_up(iA, d, 64);
    const double uB = __shfl_up(iB, d, 64);
    if (lane >= d) { iA += f * uA; iB += f * uB; }
    f *= f;
  }
  double eA = __shfl_up(iA, 1, 64);
  double eB = __shfl_up(iB, 1, 64);
  if (lane == 0) { eA = 0.0; eB = 0.0; }
  if (lane == 63) { wred[w * 2] = iA; wred[w * 2 + 1] = iB; }
  __syncthreads();
  const double mlane = mpow(m, lane);
  if (w == 1) { eA += wred[0] * mlane; eB += wred[1] * mlane; }

  const double mt  = mpow(m, t);
  const double hmg = mpow(m, b * TCH + t);
  double A = eA + xA * mt + (double)A0p[0] * hmg;
  double B = eB + xB * mt + (double)B0p[0] * hmg;

  double sum = 0.0;
  #pragma unroll
  for (int k = 0; k < SCHUNK; ++k) {
    const double rv = (double)lr[t * LPAD + k];
    const double dA = ETA * (rv - A);
    const double dB = ETA * (rv * rv - B);
    double var = B - A * A;
    var = var > EPS ? var : EPS;
    const double num = B * dA - 0.5 * A * dB;
    const float inv = rsqrtf((float)var);
    sum += num * (double)(inv * inv * inv);
    A += dA;
    B += dB;
  }
  #pragma unroll
  for (int d = 32; d >= 1; d >>= 1) sum += __shfl_xor(sum, d, 64);
  __syncthreads();
  if (lane == 0) wred[w] = sum;
  __syncthreads();
  if (t == 0) {
    atomicAdd(acc, wred[0] + wred[1]);
    __threadfence();
    const unsigned old = atomicAdd(cnt, 1u);
    if (old == TBLK - 1) {
      const double v = atomicAdd(acc, 0.0);
      out[0] = (float)(-v / (double)BATCH);
    }
  }
}

extern "C" void kernel_launch(void* const* d_in, const int* in_sizes, int n_in,
                              void* d_out, int out_size, void* d_ws, size_t ws_size,
                              hipStream_t stream) {
  const float* W  = (const float*)d_in[0];
  const float* X  = (const float*)d_in[1];
  const float* A0 = (const float*)d_in[2];
  const float* B0 = (const float*)d_in[3];

  char* ws = (char*)d_ws;
  float*  R  = (float*)ws;                                 // 1 MB
  double* SA = (double*)(ws + (size_t)BATCH * 4);          // 64 KB
  double* SB = SA + NSC;                                   // 64 KB
  double* acc = SB + NSC;                                  // 8 B
  unsigned* cnt = (unsigned*)(acc + 1);                    // 4 B

  hipMemsetAsync(acc, 0, 16, stream);   // acc + cnt
  k_rows<<<NBLK, 256, 0, stream>>>(W, X, R, SA, SB);
  k_tail<<<TBLK, 128, 0, stream>>>(R, SA, SB, A0, B0, acc, cnt, (float*)d_out);
}

// Round 8
// 50.167 us; speedup vs baseline: 3.0616x; 1.0919x over previous
//
#include <hip/hip_runtime.h>
#include <math.h>

#define BATCH     262144
#define NASSETS   128
#define TILE_ROWS 32                     // rows per K1 block (= one scan chunk)
#define NBLK      (BATCH / TILE_ROWS)    // 8192
#define SCHUNK    32                     // scan / replay chunk (rows)
#define NSC       (BATCH / SCHUNK)       // 8192 chunks
#define TBLK      64                     // k_tail blocks
#define TCH       (NSC / TBLK)           // 128 chunks per tail block
#define ETA       0.01
#define CDECAY    0.99
#define EPS       1e-8
#define LPAD      33

__device__ __forceinline__ float dot4(float4 a, float4 b) {
  return a.x * b.x + a.y * b.y + a.z * b.z + a.w * b.w;
}

// base^e by square-multiply, e < 8192 (13 bits).
__device__ __forceinline__ double mpow(double base, int e) {
  double r = 1.0, p = base;
  #pragma unroll
  for (int b = 0; b < 13; ++b) { if (e & (1 << b)) r *= p; p *= p; }
  return r;
}

// K1: global_load_lds staging, 32-row tiles. LDS 37.3KB -> 4 blocks/CU, so
// the per-CU DMA queue stays fed across other blocks' barrier/compute phases
// (R6's 2 blocks/CU left coverage dips). Block 0 also zeroes acc/cnt,
// replacing the separate memset dispatch (kernel boundary = device fence).
__global__ __launch_bounds__(256) void k_rows(
    const float* __restrict__ W, const float* __restrict__ X,
    float* __restrict__ R, double* __restrict__ SA, double* __restrict__ SB,
    double* __restrict__ acc, unsigned* __restrict__ cnt) {
  __shared__ float wbuf[TILE_ROWS * NASSETS];   // 16 KB
  __shared__ float xbuf[TILE_ROWS * NASSETS];   // 16 KB
  __shared__ float part[TILE_ROWS * LPAD];      // 4.2 KB
  __shared__ float hs[256];                     // 1 KB
  const int t   = threadIdx.x;
  const int blk = blockIdx.x;
  const int w   = t >> 6, l = t & 63;
  const float4* W4 = reinterpret_cast<const float4*>(W) + (size_t)blk * 1024;
  const float4* X4 = reinterpret_cast<const float4*>(X) + (size_t)blk * 1024;

  if (blk == 0 && t == 0) { acc[0] = 0.0; cnt[0] = 0u; }

  // Stage: 32 x 1KB DMA instrs (16B/lane, linear LDS dest = base + lane*16).
  #pragma unroll
  for (int j = 0; j < 4; ++j) {
    const int seg = w * 4 + j;                  // 0..15 (256-float segment)
    const float4* gw = W4 + seg * 64 + l;
    const float4* gx = X4 + seg * 64 + l;
    __builtin_amdgcn_global_load_lds(
        (const __attribute__((address_space(1))) void*)gw,
        (__attribute__((address_space(3))) void*)&wbuf[seg * 256], 16, 0, 0);
    __builtin_amdgcn_global_load_lds(
        (const __attribute__((address_space(1))) void*)gx,
        (__attribute__((address_space(3))) void*)&xbuf[seg * 256], 16, 0, 0);
  }
  __syncthreads();                              // drains vmcnt (DMA complete)

  // Partial dots: contiguous ds_read_b128 (conflict-free), padded writes.
  #pragma unroll
  for (int p = 0; p < 4; ++p) {
    const int idx = p * 256 + t;
    const float4 a = reinterpret_cast<const float4*>(wbuf)[idx];
    const float4 b = reinterpret_cast<const float4*>(xbuf)[idx];
    part[(idx >> 5) * LPAD + (idx & 31)] = dot4(a, b);
  }
  __syncthreads();

  // Eighth-row sums (all 256 threads), then 32 threads finish + carry.
  {
    const int row = t & 31, q = t >> 5;         // q = 0..7, 4 cols each
    float s = 0.f;
    #pragma unroll
    for (int j = 0; j < 4; ++j) s += part[row * LPAD + q * 4 + j];
    hs[t] = s;
  }
  __syncthreads();
  if (t < TILE_ROWS) {
    float sum = 0.f;
    #pragma unroll
    for (int q = 0; q < 8; ++q) sum += hs[t + q * 32];
    R[(size_t)blk * TILE_ROWS + t] = sum;

    const int e = 31 - t;                   // wgt = ETA * c^e via square-select
    const double c1 = CDECAY, c2 = c1*c1, c4 = c2*c2, c8 = c4*c4, c16 = c8*c8;
    double wgt = ETA;
    if (e & 1)  wgt *= c1;
    if (e & 2)  wgt *= c2;
    if (e & 4)  wgt *= c4;
    if (e & 8)  wgt *= c8;
    if (e & 16) wgt *= c16;
    const double r = (double)sum;
    double sA = wgt * r, sB = wgt * r * r;
    sA += __shfl_xor(sA, 16, 64); sB += __shfl_xor(sB, 16, 64);
    sA += __shfl_xor(sA,  8, 64); sB += __shfl_xor(sB,  8, 64);
    sA += __shfl_xor(sA,  4, 64); sB += __shfl_xor(sB,  4, 64);
    sA += __shfl_xor(sA,  2, 64); sB += __shfl_xor(sB,  2, 64);
    sA += __shfl_xor(sA,  1, 64); sB += __shfl_xor(sB,  1, 64);
    if (t == 0) { SA[blk] = sA; SB[blk] = sB; }
  }
}

// K2 (k_tail): 64 INDEPENDENT blocks x 128 threads (unchanged from R5/R6).
// Incoming carry recomputed redundantly from the 256-chunk predecessor
// window (older terms carry c^8192 ~ 1.6e-36 -> dropped).
__global__ __launch_bounds__(128) void k_tail(
    const float* __restrict__ R, const double* __restrict__ SA,
    const double* __restrict__ SB, const float* __restrict__ A0p,
    const float* __restrict__ B0p, double* __restrict__ acc,
    unsigned* __restrict__ cnt, float* __restrict__ out) {
  __shared__ float  lr[TCH * LPAD];     // 16.9 KB
  __shared__ double wred[4];
  const int t = threadIdx.x;            // 0..127
  const int b = blockIdx.x;             // 0..63
  const int lane = t & 63, w = t >> 6;

  const float* Rb = R + (size_t)b * (TCH * SCHUNK);
  #pragma unroll
  for (int q = 0; q < 32; ++q) {
    const int fi = q * 128 + t;
    lr[(fi >> 5) * LPAD + (fi & 31)] = Rb[fi];
  }

  double m = CDECAY;                    // -> c^32 (per-chunk factor)
  #pragma unroll
  for (int q = 0; q < 5; ++q) m = m * m;

  // Incoming carry from the 256-chunk predecessor window.
  const int wbase = b * TCH - 256;
  double xA = 0.0, xB = 0.0;
  #pragma unroll
  for (int s = 0; s < 2; ++s) {
    const int j = t + s * 128;
    const int g = wbase + j;
    if (g >= 0) {
      const double wgt = mpow(m, 255 - j);
      xA += wgt * SA[g];
      xB += wgt * SB[g];
    }
  }
  #pragma unroll
  for (int d = 32; d >= 1; d >>= 1) {
    xA += __shfl_xor(xA, d, 64);
    xB += __shfl_xor(xB, d, 64);
  }
  if (lane == 0) { wred[w * 2] = xA; wred[w * 2 + 1] = xB; }
  __syncthreads();
  xA = wred[0] + wred[2];
  xB = wred[1] + wred[3];
  __syncthreads();

  // Own chunk values + exclusive scan (factor m) across the 128 chunks.
  const int c = b * TCH + t;
  double iA = SA[c], iB = SB[c], f = m;
  #pragma unroll
  for (int d = 1; d < 64; d <<= 1) {
    const double uA = __shfl_up(iA, d, 64);
    const double uB = __shfl_up(iB, d, 64);
    if (lane >= d) { iA += f * uA; iB += f * uB; }
    f *= f;
  }
  double eA = __shfl_up(iA, 1, 64);
  double eB = __shfl_up(iB, 1, 64);
  if (lane == 0) { eA = 0.0; eB = 0.0; }
  if (lane == 63) { wred[w * 2] = iA; wred[w * 2 + 1] = iB; }
  __syncthreads();
  const double mlane = mpow(m, lane);
  if (w == 1) { eA += wred[0] * mlane; eB += wred[1] * mlane; }

  const double mt  = mpow(m, t);
  const double hmg = mpow(m, b * TCH + t);
  double A = eA + xA * mt + (double)A0p[0] * hmg;
  double B = eB + xB * mt + (double)B0p[0] * hmg;

  double sum = 0.0;
  #pragma unroll
  for (int k = 0; k < SCHUNK; ++k) {
    const double rv = (double)lr[t * LPAD + k];
    const double dA = ETA * (rv - A);
    const double dB = ETA * (rv * rv - B);
    double var = B - A * A;
    var = var > EPS ? var : EPS;
    const double num = B * dA - 0.5 * A * dB;
    const float inv = rsqrtf((float)var);
    sum += num * (double)(inv * inv * inv);
    A += dA;
    B += dB;
  }
  #pragma unroll
  for (int d = 32; d >= 1; d >>= 1) sum += __shfl_xor(sum, d, 64);
  __syncthreads();
  if (lane == 0) wred[w] = sum;
  __syncthreads();
  if (t == 0) {
    atomicAdd(acc, wred[0] + wred[1]);
    __threadfence();
    const unsigned old = atomicAdd(cnt, 1u);
    if (old == TBLK - 1) {
      const double v = atomicAdd(acc, 0.0);
      out[0] = (float)(-v / (double)BATCH);
    }
  }
}

extern "C" void kernel_launch(void* const* d_in, const int* in_sizes, int n_in,
                              void* d_out, int out_size, void* d_ws, size_t ws_size,
                              hipStream_t stream) {
  const float* W  = (const float*)d_in[0];
  const float* X  = (const float*)d_in[1];
  const float* A0 = (const float*)d_in[2];
  const float* B0 = (const float*)d_in[3];

  char* ws = (char*)d_ws;
  float*  R  = (float*)ws;                                 // 1 MB
  double* SA = (double*)(ws + (size_t)BATCH * 4);          // 64 KB
  double* SB = SA + NSC;                                   // 64 KB
  double* acc = SB + NSC;                                  // 8 B
  unsigned* cnt = (unsigned*)(acc + 1);                    // 4 B

  k_rows<<<NBLK, 256, 0, stream>>>(W, X, R, SA, SB, acc, cnt);
  k_tail<<<TBLK, 128, 0, stream>>>(R, SA, SB, A0, B0, acc, cnt, (float*)d_out);
}